// Round 7
// baseline (325.771 us; speedup 1.0000x reference)
//
#include <hip/hip_runtime.h>

// NonLocalBlock: B=4, C=256, Ci=128, H=W=64, N=4096.
// R7: barrier-free k_attn/k_cols — MFMA fragments loaded directly from
// global (L2-served, XCD-swizzled block mapping); only the wave-private
// Wl C->A transpose stays in LDS. k_wz reads yP once (grid 256). k_init
// restored: f16 weight cvt + zeroing.

#define B_  4
#define C_  256
#define CI  128
#define N_  4096
#define NB  (B_*N_)     // 16384
#define MB_ (1u<<20)

typedef _Float16 f16;
typedef f16   f16x8 __attribute__((ext_vector_type(8)));
typedef f16   f16x4 __attribute__((ext_vector_type(4)));
typedef float f32x4 __attribute__((ext_vector_type(4)));

#define MFMA(a,b,c) __builtin_amdgcn_mfma_f32_16x16x32_f16(a,b,c,0,0,0)

// ---- workspace byte offsets (~28.4 MB) ----
#define OFF_THETA  0                 // f16 [B][N][CI]  4 MB
#define OFF_PHI    (4u*MB_)          // f16 [B][N][CI]  4 MB
#define OFF_G      (8u*MB_)          // f16 [B][CI][N]  4 MB
#define OFF_YP     (12u*MB_)         // f16 [4][B][N][CI]  16 MB (j-quarter partials)
#define OFF_WY     0                 // f16 [B][C][N] 8 MB — overlays theta+phi (dead by k_wz)
#define OFF_D      (28u*MB_)         // f32 [NB] column exp-sums (64 KB)
#define OFF_SSUM   (OFF_D + 65536)
#define OFF_SSQ    (OFF_SSUM + 1024)
#define OFF_WCVT   (OFF_SSQ + 1024)  // f16 weights g,t,p,z  256 KB
#define PSZ ((size_t)B_*N_*CI)

// ---------------- init: weight cvt f32->f16 + zero D/ssum/ssq ----------------
__global__ void k_init(const float* gw, const float* tw, const float* pw,
                       const float* zw, f16* wcvt, float* D,
                       float* ssum, float* ssq) {
    int b = blockIdx.x, t = threadIdx.x;
    if (b < 512) {
        int i = b * 256 + t;
        const float* s;
        int which = i >> 15;
        if (which == 0) s = gw; else if (which == 1) s = tw;
        else if (which == 2) s = pw; else s = zw;
        wcvt[i] = (f16)s[i & 32767];
    } else if (b < 576) {
        D[(b - 512) * 256 + t] = 0.f;
    } else if (b == 576) ssum[t] = 0.f;
    else ssq[t] = 0.f;
}

// ---------------- fused 1x1-conv projections (all 3, one x read) ----------------
__global__ __launch_bounds__(256) void k_proj(
        const float* __restrict__ x, const f16* __restrict__ wcvt,
        const float* __restrict__ gb, const float* __restrict__ tb,
        const float* __restrict__ pb,
        f16* __restrict__ thetaT, f16* __restrict__ phiT, f16* __restrict__ gC) {
    __shared__ __align__(16) f16 xT[32 * 264];       // [n][c], stride 264
    int bb = blockIdx.x >> 7;
    int n0 = (blockIdx.x & 127) * 32;
    int t = threadIdx.x;

    const float* xb = x + (size_t)bb * C_ * N_;
    for (int rep = 0; rep < 8; rep++) {
        int lin = rep * 256 + t;
        int c = lin >> 3, np = (lin & 7) * 4;
        float4 v = *reinterpret_cast<const float4*>(xb + c * N_ + n0 + np);
        xT[(np + 0) * 264 + c] = (f16)v.x;
        xT[(np + 1) * 264 + c] = (f16)v.y;
        xT[(np + 2) * 264 + c] = (f16)v.z;
        xT[(np + 3) * 264 + c] = (f16)v.w;
    }
    __syncthreads();

    int w = t >> 6, l16 = t & 15, q = (t & 63) >> 4;
    int ci0 = w * 32;
    for (int proj = 0; proj < 3; proj++) {
        const f16* W0 = wcvt + proj * 32768;         // [128][256] f16 row-major
        f32x4 acc[2][2] = {};
        for (int kk = 0; kk < 8; kk++) {
            f16x8 a0 = *reinterpret_cast<const f16x8*>(W0 + (ci0 + l16) * 256 + kk * 32 + q * 8);
            f16x8 a1 = *reinterpret_cast<const f16x8*>(W0 + (ci0 + 16 + l16) * 256 + kk * 32 + q * 8);
#pragma unroll
            for (int nt = 0; nt < 2; nt++) {
                f16x8 bv = *reinterpret_cast<const f16x8*>(&xT[(nt * 16 + l16) * 264 + kk * 32 + q * 8]);
                acc[0][nt] = MFMA(a0, bv, acc[0][nt]);
                acc[1][nt] = MFMA(a1, bv, acc[1][nt]);
            }
        }
        const float* bias = (proj == 0) ? gb : (proj == 1) ? tb : pb;
#pragma unroll
        for (int a = 0; a < 2; a++) {
#pragma unroll
            for (int nt = 0; nt < 2; nt++) {
                int n = n0 + nt * 16 + l16;
                int cib = ci0 + a * 16 + q * 4;
                if (proj == 0) {
#pragma unroll
                    for (int r = 0; r < 4; r++)
                        gC[((size_t)bb * CI + cib + r) * N_ + n] = (f16)(acc[a][nt][r] + bias[cib + r]);
                } else {
                    f16x4 v4;
#pragma unroll
                    for (int r = 0; r < 4; r++) v4[r] = (f16)(acc[a][nt][r] + bias[cib + r]);
                    f16* dst = (proj == 1 ? thetaT : phiT) + ((size_t)bb * N_ + n) * CI + cib;
                    *reinterpret_cast<f16x4*>(dst) = v4;
                }
            }
        }
    }
}

// ---------------- pass 2: column exp-sums, barrier-free, frags from L2 ----------------
// XCD swizzle: group blocks on one XCD by (bb,isp) so the theta slice stays L2-hot.
__global__ __launch_bounds__(256, 2) void k_cols(
        const f16* __restrict__ thetaT, const f16* __restrict__ phiT,
        float* __restrict__ D) {
    int bid = blockIdx.x;                // 512
    int xcd = bid & 7, slot = bid >> 3;  // 64 slots per XCD
    int combo = xcd * 4 + (slot & 3);    // 32 combos = bb(4) x isp(8)
    int isp = combo & 7, bb = combo >> 3;
    int jb = slot >> 2;                  // 0..15
    int t = threadIdx.x, w = t >> 6, l16 = t & 15, q = (t & 63) >> 4;
    int jw0 = jb * 256 + w * 64;

    f16x8 pf[4][4];
    const f16* pb = phiT + ((size_t)bb * N_ + jw0) * CI;
#pragma unroll
    for (int jt = 0; jt < 4; jt++)
#pragma unroll
        for (int kk = 0; kk < 4; kk++)
            pf[jt][kk] = *reinterpret_cast<const f16x8*>(pb + (jt * 16 + l16) * CI + kk * 32 + q * 8);

    const f16* thB = thetaT + ((size_t)bb * N_ + isp * 512 + l16) * CI + q * 8;
    float s[4] = {0.f, 0.f, 0.f, 0.f};
    for (int ic = 0; ic < 32; ic++) {
        const f16* ta = thB + (size_t)ic * 16 * CI;
        f16x8 av[4];
#pragma unroll
        for (int kk = 0; kk < 4; kk++)
            av[kk] = *reinterpret_cast<const f16x8*>(ta + kk * 32);
        f32x4 f[4] = {};
#pragma unroll
        for (int kk = 0; kk < 4; kk++)
#pragma unroll
            for (int jt = 0; jt < 4; jt++)
                f[jt] = MFMA(av[kk], pf[jt][kk], f[jt]);
#pragma unroll
        for (int jt = 0; jt < 4; jt++)
            s[jt] += __expf(f[jt][0]) + __expf(f[jt][1])
                   + __expf(f[jt][2]) + __expf(f[jt][3]);
    }
#pragma unroll
    for (int jt = 0; jt < 4; jt++) {
        s[jt] += __shfl_xor(s[jt], 16);
        s[jt] += __shfl_xor(s[jt], 32);
    }
    if (q == 0) {
#pragma unroll
        for (int jt = 0; jt < 4; jt++)
            atomicAdd(&D[bb * N_ + jw0 + jt * 16 + l16], s[jt]);
    }
}

// ---------------- pass 3: y = softmax(f) @ g — barrier-free ----------------
// block = 128 i (4 waves x 32 i), 4-way j-split; phi/g fragments straight
// from global (L2, XCD-grouped by (bb,jq)); only the wave-private Wl
// transpose uses LDS. No __syncthreads anywhere.
__global__ __launch_bounds__(256, 2) void k_attn(
        const f16* __restrict__ thetaT, const f16* __restrict__ phiT,
        const f16* __restrict__ gC, const float* __restrict__ D,
        f16* __restrict__ yP) {
    __shared__ __align__(16) f16 smem[4 * 4352];     // per-wave 8704 B: Wl [32][36], epilogue [32][136]

    int bid = blockIdx.x;                // 512
    int xcd = bid & 7, slot = bid >> 3;  // 64 slots per XCD
    int combo = xcd * 2 + (slot & 1);    // 16 combos = bb(4) x jq(4)
    int bb = combo >> 2, jq = combo & 3;
    int i0 = (slot >> 1) * 128;          // 0..31 -> 32 i-tiles
    int t = threadIdx.x, w = t >> 6, l = t & 63, l16 = t & 15, q = (t & 63) >> 4;
    int jbase = jq * 1024;

    f16x8 ta[2][4];
    const f16* tb = thetaT + ((size_t)bb * N_ + i0 + w * 32 + l16) * CI;
#pragma unroll
    for (int s = 0; s < 2; s++)
#pragma unroll
        for (int kk = 0; kk < 4; kk++)
            ta[s][kk] = *reinterpret_cast<const f16x8*>(tb + s * 16 * CI + kk * 32 + q * 8);

    const f16* phiB = phiT + (size_t)bb * N_ * CI;
    const f16* gB   = gC   + (size_t)bb * CI * N_;
    const float* Dpb = D + bb * N_;

    f32x4 yacc[2][8] = {};
    f16* Wlw = smem + w * 4352;
    for (int jt = 0; jt < 16; jt++) {
        int j0 = jbase + jt * 64;
#pragma unroll
        for (int jh = 0; jh < 2; jh++) {
            // f-phase: two 16-j subtiles of this 32-j half, frags from global
#pragma unroll
            for (int js2 = 0; js2 < 2; js2++) {
                int js = jh * 2 + js2;
                f32x4 f0 = {0,0,0,0}, f1 = {0,0,0,0};
#pragma unroll
                for (int kk = 0; kk < 4; kk++) {
                    f16x8 pv = *reinterpret_cast<const f16x8*>(
                        phiB + (size_t)(j0 + js * 16 + l16) * CI + kk * 32 + q * 8);
                    f0 = MFMA(ta[0][kk], pv, f0);
                    f1 = MFMA(ta[1][kk], pv, f1);
                }
                float mdv = __logf(Dpb[j0 + js * 16 + l16]);
#pragma unroll
                for (int r = 0; r < 4; r++) {
                    Wlw[(q * 4 + r) * 36 + js2 * 16 + l16]      = (f16)__expf(f0[r] - mdv);
                    Wlw[(16 + q * 4 + r) * 36 + js2 * 16 + l16] = (f16)__expf(f1[r] - mdv);
                }
            }
            // PV: Wl same-wave RAW (in-order DS); g frags from global
            f16x8 wf0 = *reinterpret_cast<const f16x8*>(&Wlw[l16 * 36 + q * 8]);
            f16x8 wf1 = *reinterpret_cast<const f16x8*>(&Wlw[(16 + l16) * 36 + q * 8]);
#pragma unroll
            for (int d = 0; d < 8; d++) {
                f16x8 gv = *reinterpret_cast<const f16x8*>(
                    gB + (size_t)(d * 16 + l16) * N_ + j0 + jh * 32 + q * 8);
                yacc[0][d] = MFMA(wf0, gv, yacc[0][d]);
                yacc[1][d] = MFMA(wf1, gv, yacc[1][d]);
            }
        }
    }
    // epilogue: per-wave transpose C-layout -> [i][c] via the same wave region
#pragma unroll
    for (int s = 0; s < 2; s++)
#pragma unroll
        for (int d = 0; d < 8; d++)
#pragma unroll
            for (int r = 0; r < 4; r++)
                Wlw[(s * 16 + q * 4 + r) * 136 + d * 16 + l16] = (f16)yacc[s][d][r];
    f16* yo = yP + (size_t)jq * PSZ + ((size_t)bb * N_ + i0 + w * 32) * CI;
#pragma unroll
    for (int rr = 0; rr < 8; rr++) {
        int chunk = rr * 64 + l;
        int il = chunk >> 4, u = chunk & 15;
        *reinterpret_cast<f16x8*>(yo + il * CI + u * 8) =
            *reinterpret_cast<const f16x8*>(&Wlw[il * 136 + u * 8]);
    }
}

// ---------------- pass 4: w_y = wz @ (sum of y partials) + b, channel sums ----------------
// grid 256: block = bb(4) x nb(64 n-tiles of 64); reads its yP slice ONCE,
// computes all 256 output channels (wave w owns o-range w*64..+64).
__global__ __launch_bounds__(256) void k_wz(
        const f16* __restrict__ wzc, const f16* __restrict__ yP,
        const float* __restrict__ zb, f16* __restrict__ wy,
        float* __restrict__ ssum, float* __restrict__ ssq) {
    int id = blockIdx.x;                  // 256
    int nb = id & 63, bb = id >> 6;
    int t = threadIdx.x, w = t >> 6, l16 = t & 15, q = (t & 63) >> 4;
    int o0 = w * 64, n0 = nb * 64;
    f32x4 acc[4][4] = {};                 // [os][nt]
#pragma unroll
    for (int kk = 0; kk < 4; kk++) {
        f16x8 bv[4];
#pragma unroll
        for (int nt = 0; nt < 4; nt++) {
            size_t yi = ((size_t)bb * N_ + n0 + nt * 16 + l16) * CI + kk * 32 + q * 8;
            f16x8 b0 = *reinterpret_cast<const f16x8*>(yP + yi);
            f16x8 b1 = *reinterpret_cast<const f16x8*>(yP + PSZ + yi);
            f16x8 b2 = *reinterpret_cast<const f16x8*>(yP + 2 * PSZ + yi);
            f16x8 b3 = *reinterpret_cast<const f16x8*>(yP + 3 * PSZ + yi);
            bv[nt] = (b0 + b1) + (b2 + b3);
        }
#pragma unroll
        for (int os = 0; os < 4; os++) {
            f16x8 av = *reinterpret_cast<const f16x8*>(
                wzc + (o0 + os * 16 + l16) * CI + kk * 32 + q * 8);
#pragma unroll
            for (int nt = 0; nt < 4; nt++)
                acc[os][nt] = MFMA(av, bv[nt], acc[os][nt]);
        }
    }
#pragma unroll
    for (int os = 0; os < 4; os++)
#pragma unroll
    for (int r = 0; r < 4; r++) {
        int o = o0 + os * 16 + q * 4 + r;
        float bias = zb[o];
        float sr = 0.f, qr = 0.f;
#pragma unroll
        for (int nt = 0; nt < 4; nt++) {
            float v = acc[os][nt][r] + bias;
            wy[((size_t)bb * C_ + o) * N_ + n0 + nt * 16 + l16] = (f16)v;
            sr += v; qr += v * v;
        }
#pragma unroll
        for (int off = 1; off < 16; off <<= 1) {
            sr += __shfl_xor(sr, off);
            qr += __shfl_xor(qr, off);
        }
        if (l16 == 0) { atomicAdd(&ssum[o], sr); atomicAdd(&ssq[o], qr); }
    }
}

// ---------------- pass 5: BN (stats inline) + residual ----------------
__global__ void k_final(const f16* __restrict__ wy, const float* __restrict__ x,
                        const float* __restrict__ ssum, const float* __restrict__ ssq,
                        const float* __restrict__ gamma, const float* __restrict__ beta,
                        float* __restrict__ out) {
    int p = blockIdx.x * 256 + threadIdx.x;           // 512K groups of 8
    int c = (p >> 9) & 255;
    const float inv = 1.0f / 16384.0f;
    float mean = ssum[c] * inv;
    float var = ssq[c] * inv - mean * mean;
    float s = gamma[c] * rsqrtf(var + 1e-5f);
    float h = beta[c] - mean * s;
    f16x8 wv = reinterpret_cast<const f16x8*>(wy)[p];
    float4 x0 = reinterpret_cast<const float4*>(x)[2 * p];
    float4 x1 = reinterpret_cast<const float4*>(x)[2 * p + 1];
    float4 o0, o1;
    o0.x = (float)wv[0] * s + h + x0.x;
    o0.y = (float)wv[1] * s + h + x0.y;
    o0.z = (float)wv[2] * s + h + x0.z;
    o0.w = (float)wv[3] * s + h + x0.w;
    o1.x = (float)wv[4] * s + h + x1.x;
    o1.y = (float)wv[5] * s + h + x1.y;
    o1.z = (float)wv[6] * s + h + x1.z;
    o1.w = (float)wv[7] * s + h + x1.w;
    reinterpret_cast<float4*>(out)[2 * p] = o0;
    reinterpret_cast<float4*>(out)[2 * p + 1] = o1;
}

extern "C" void kernel_launch(void* const* d_in, const int* in_sizes, int n_in,
                              void* d_out, int out_size, void* d_ws, size_t ws_size,
                              hipStream_t stream) {
    const float* x     = (const float*)d_in[0];
    const float* gw    = (const float*)d_in[1];
    const float* gb    = (const float*)d_in[2];
    const float* tw    = (const float*)d_in[3];
    const float* tbv   = (const float*)d_in[4];
    const float* pw    = (const float*)d_in[5];
    const float* pb    = (const float*)d_in[6];
    const float* zw    = (const float*)d_in[7];
    const float* zb    = (const float*)d_in[8];
    const float* gamma = (const float*)d_in[9];
    const float* beta  = (const float*)d_in[10];

    char* ws = (char*)d_ws;
    f16* thetaT = (f16*)(ws + OFF_THETA);
    f16* phiT   = (f16*)(ws + OFF_PHI);
    f16* gC     = (f16*)(ws + OFF_G);
    f16* yP     = (f16*)(ws + OFF_YP);
    f16* wy     = (f16*)(ws + OFF_WY);
    f16* wcvt   = (f16*)(ws + OFF_WCVT);
    float* D    = (float*)(ws + OFF_D);
    float* ssum = (float*)(ws + OFF_SSUM);
    float* ssq  = (float*)(ws + OFF_SSQ);

    k_init<<<578, 256, 0, stream>>>(gw, tw, pw, zw, wcvt, D, ssum, ssq);
    k_proj<<<512, 256, 0, stream>>>(x, wcvt, gb, tbv, pb, thetaT, phiT, gC);
    k_cols<<<512, 256, 0, stream>>>(thetaT, phiT, D);
    k_attn<<<512, 256, 0, stream>>>(thetaT, phiT, gC, D, yP);
    k_wz<<<256, 256, 0, stream>>>(wcvt + 3 * 32768, yP, zb, wy, ssum, ssq);
    k_final<<<2048, 256, 0, stream>>>(wy, x, ssum, ssq, gamma, beta, (float*)d_out);
}

// Round 8
// 252.148 us; speedup vs baseline: 1.2920x; 1.2920x over previous
//
#include <hip/hip_runtime.h>

// NonLocalBlock: B=4, C=256, Ci=128, H=W=64, N=4096.
// R8: k_attn = R6 verbatim (67us, staged LDS; R7 direct-global regressed 2x).
// Occupancy push on the small kernels: k_proj split by proj (grid 512x3,
// 6 blocks/CU), k_cols i-split 16 (grid 1024), k_wz n-tile 32 (grid 2048).

#define B_  4
#define C_  256
#define CI  128
#define N_  4096
#define NB  (B_*N_)     // 16384
#define MB_ (1u<<20)

typedef _Float16 f16;
typedef f16   f16x8 __attribute__((ext_vector_type(8)));
typedef f16   f16x4 __attribute__((ext_vector_type(4)));
typedef float f32x4 __attribute__((ext_vector_type(4)));

#define MFMA(a,b,c) __builtin_amdgcn_mfma_f32_16x16x32_f16(a,b,c,0,0,0)

// async global->LDS, 16B per lane; LDS dest = wave-uniform base + lane*16
#define GLD16(g, lp) __builtin_amdgcn_global_load_lds( \
    (const __attribute__((address_space(1))) void*)(g), \
    (__attribute__((address_space(3))) void*)(lp), 16, 0, 0)

// ---- workspace byte offsets (~28.4 MB) ----
#define OFF_THETA  0                 // f16 [B][N][CI]  4 MB
#define OFF_PHI    (4u*MB_)          // f16 [B][N][CI]  4 MB
#define OFF_G      (8u*MB_)          // f16 [B][CI][N]  4 MB
#define OFF_YP     (12u*MB_)         // f16 [4][B][N][CI]  16 MB (j-quarter partials)
#define OFF_WY     0                 // f16 [B][C][N] 8 MB — overlays theta+phi (dead by k_wz)
#define OFF_D      (28u*MB_)         // f32 [NB] column exp-sums (64 KB)
#define OFF_SSUM   (OFF_D + 65536)
#define OFF_SSQ    (OFF_SSUM + 1024)
#define OFF_WCVT   (OFF_SSQ + 1024)  // f16 weights g,t,p,z  256 KB
#define PSZ ((size_t)B_*N_*CI)

// ---------------- init: weight cvt f32->f16 + zero D/ssum/ssq ----------------
__global__ void k_init(const float* gw, const float* tw, const float* pw,
                       const float* zw, f16* wcvt, float* D,
                       float* ssum, float* ssq) {
    int b = blockIdx.x, t = threadIdx.x;
    if (b < 512) {
        int i = b * 256 + t;
        const float* s;
        int which = i >> 15;
        if (which == 0) s = gw; else if (which == 1) s = tw;
        else if (which == 2) s = pw; else s = zw;
        wcvt[i] = (f16)s[i & 32767];
    } else if (b < 576) {
        D[(b - 512) * 256 + t] = 0.f;
    } else if (b == 576) ssum[t] = 0.f;
    else ssq[t] = 0.f;
}

// ---------------- fused 1x1-conv projections, one proj per block ----------------
// grid (512, 3): x tile re-staged per proj (L3-served), 6 blocks/CU.
__global__ __launch_bounds__(256) void k_proj(
        const float* __restrict__ x, const f16* __restrict__ wcvt,
        const float* __restrict__ gb, const float* __restrict__ tb,
        const float* __restrict__ pb,
        f16* __restrict__ thetaT, f16* __restrict__ phiT, f16* __restrict__ gC) {
    __shared__ __align__(16) f16 xT[32 * 264];       // [n][c], stride 264
    int proj = blockIdx.y;
    int bb = blockIdx.x >> 7;
    int n0 = (blockIdx.x & 127) * 32;
    int t = threadIdx.x;

    const float* xb = x + (size_t)bb * C_ * N_;
    for (int rep = 0; rep < 8; rep++) {
        int lin = rep * 256 + t;
        int c = lin >> 3, np = (lin & 7) * 4;
        float4 v = *reinterpret_cast<const float4*>(xb + c * N_ + n0 + np);
        xT[(np + 0) * 264 + c] = (f16)v.x;
        xT[(np + 1) * 264 + c] = (f16)v.y;
        xT[(np + 2) * 264 + c] = (f16)v.z;
        xT[(np + 3) * 264 + c] = (f16)v.w;
    }
    __syncthreads();

    int w = t >> 6, l16 = t & 15, q = (t & 63) >> 4;
    int ci0 = w * 32;
    const f16* W0 = wcvt + proj * 32768;             // [128][256] f16 row-major
    f32x4 acc[2][2] = {};
    for (int kk = 0; kk < 8; kk++) {
        f16x8 a0 = *reinterpret_cast<const f16x8*>(W0 + (ci0 + l16) * 256 + kk * 32 + q * 8);
        f16x8 a1 = *reinterpret_cast<const f16x8*>(W0 + (ci0 + 16 + l16) * 256 + kk * 32 + q * 8);
#pragma unroll
        for (int nt = 0; nt < 2; nt++) {
            f16x8 bv = *reinterpret_cast<const f16x8*>(&xT[(nt * 16 + l16) * 264 + kk * 32 + q * 8]);
            acc[0][nt] = MFMA(a0, bv, acc[0][nt]);
            acc[1][nt] = MFMA(a1, bv, acc[1][nt]);
        }
    }
    const float* bias = (proj == 0) ? gb : (proj == 1) ? tb : pb;
#pragma unroll
    for (int a = 0; a < 2; a++) {
#pragma unroll
        for (int nt = 0; nt < 2; nt++) {
            int n = n0 + nt * 16 + l16;
            int cib = ci0 + a * 16 + q * 4;
            if (proj == 0) {
#pragma unroll
                for (int r = 0; r < 4; r++)
                    gC[((size_t)bb * CI + cib + r) * N_ + n] = (f16)(acc[a][nt][r] + bias[cib + r]);
            } else {
                f16x4 v4;
#pragma unroll
                for (int r = 0; r < 4; r++) v4[r] = (f16)(acc[a][nt][r] + bias[cib + r]);
                f16* dst = (proj == 1 ? thetaT : phiT) + ((size_t)bb * N_ + n) * CI + cib;
                *reinterpret_cast<f16x4*>(dst) = v4;
            }
        }
    }
}

// ---------------- pass 2: column exp-sums (staged theta), atomic into D ----------------
// grid 1024 = bb(4) x jb(16) x isp(16); i-slice 256 = 4 staged tiles of 64.
__global__ __launch_bounds__(256, 2) void k_cols(
        const f16* __restrict__ thetaT, const f16* __restrict__ phiT,
        float* __restrict__ D) {
    __shared__ __align__(16) f16 thS[2][64 * 128];
    int id = blockIdx.x;                 // 1024
    int isp = id & 15, jb = (id >> 4) & 15, bb = id >> 8;
    int t = threadIdx.x, w = t >> 6, l = t & 63, l16 = t & 15, q = (t & 63) >> 4;
    int jw0 = jb * 256 + w * 64;

    f16x8 pf[4][4];
    const f16* pb = phiT + ((size_t)bb * N_ + jw0) * CI;
#pragma unroll
    for (int jt = 0; jt < 4; jt++)
#pragma unroll
        for (int kk = 0; kk < 4; kk++)
            pf[jt][kk] = *reinterpret_cast<const f16x8*>(pb + (jt * 16 + l16) * CI + kk * 32 + q * 8);

    const f16* thB = thetaT + ((size_t)bb * N_ + isp * 256) * CI;
    auto stage = [&](int bf, int it0) {
#pragma unroll
        for (int r = 0; r < 4; r++) {
            int p = r * 256 + w * 64 + l;
            int pi = p >> 4, pu = (p & 15) ^ (pi & 15);
            const char* ga = (const char*)(thB + (size_t)(it0 + pi) * CI) + pu * 16;
            GLD16(ga, &thS[bf][(r * 256 + w * 64) * 8]);
        }
    };

    float s[4] = {0.f, 0.f, 0.f, 0.f};
    stage(0, 0);
    __syncthreads();
    for (int it = 0; it < 4; it++) {
        int bf = it & 1;
        if (it + 1 < 4) stage(bf ^ 1, (it + 1) * 64);
#pragma unroll
        for (int ic = 0; ic < 4; ic++) {
            f16x8 av[4];
#pragma unroll
            for (int kk = 0; kk < 4; kk++)
                av[kk] = *reinterpret_cast<const f16x8*>(
                    &thS[bf][(ic * 16 + l16) * 128 + (((kk * 4 + q) ^ l16) * 8)]);
            f32x4 f[4] = {};
#pragma unroll
            for (int kk = 0; kk < 4; kk++)
#pragma unroll
                for (int jt = 0; jt < 4; jt++)
                    f[jt] = MFMA(av[kk], pf[jt][kk], f[jt]);
#pragma unroll
            for (int jt = 0; jt < 4; jt++)
                s[jt] += __expf(f[jt][0]) + __expf(f[jt][1])
                       + __expf(f[jt][2]) + __expf(f[jt][3]);
        }
        __syncthreads();
    }
#pragma unroll
    for (int jt = 0; jt < 4; jt++) {
        s[jt] += __shfl_xor(s[jt], 16);
        s[jt] += __shfl_xor(s[jt], 32);
    }
    if (q == 0) {
#pragma unroll
        for (int jt = 0; jt < 4; jt++)
            atomicAdd(&D[bb * N_ + jw0 + jt * 16 + l16], s[jt]);
    }
}

// ---------------- pass 3: y = softmax(f) @ g  (R6 body, unchanged) ----------------
__global__ __launch_bounds__(256, 2) void k_attn(
        const f16* __restrict__ thetaT, const f16* __restrict__ phiT,
        const f16* __restrict__ gC, const float* __restrict__ D,
        f16* __restrict__ yP) {
    __shared__ __align__(16) char smem[74752];
    f16 (*phiS)[64 * 128] = (f16(*)[64 * 128])smem;            // 2 x 16 KB
    f16 (*gS)[128 * 64]   = (f16(*)[128 * 64])(smem + 32768);  // 2 x 16 KB
    f16* Wl  = (f16*)(smem + 65536);                           // 4 x [32][36] = 9 KB
    f16* yTr = (f16*)smem;                                     // epilogue overlay

    int jq = blockIdx.x & 3;
    int ib = blockIdx.x >> 2;          // 0..127
    int bb = ib >> 5;
    int i0 = (ib & 31) * 128;
    int t = threadIdx.x, w = t >> 6, l = t & 63, l16 = t & 15, q = (t & 63) >> 4;
    int jbase = jq * 1024;

    f16x8 ta[2][4];
    const f16* tb = thetaT + ((size_t)bb * N_ + i0 + w * 32 + l16) * CI;
#pragma unroll
    for (int s = 0; s < 2; s++)
#pragma unroll
        for (int kk = 0; kk < 4; kk++)
            ta[s][kk] = *reinterpret_cast<const f16x8*>(tb + s * 16 * CI + kk * 32 + q * 8);

    const f16* phiB = phiT + (size_t)bb * N_ * CI;
    const f16* gB   = gC   + (size_t)bb * CI * N_;
    const float* Dpb = D + bb * N_;

    auto stage = [&](int bf, int j0g) {
#pragma unroll
        for (int r = 0; r < 4; r++) {
            int p = r * 256 + w * 64 + l;
            int ub = (r * 256 + w * 64) * 8;          // wave-uniform LDS base (f16)
            int pj = p >> 4, pu = (p & 15) ^ (pj & 15);
            const char* ga = (const char*)(phiB + (size_t)(j0g + pj) * CI) + pu * 16;
            GLD16(ga, &phiS[bf][ub]);
            int pc = p >> 3, pu2 = (p & 7) ^ (pc & 7);
            const char* ga2 = (const char*)(gB + (size_t)pc * N_ + j0g) + pu2 * 16;
            GLD16(ga2, &gS[bf][ub]);
        }
    };

    f32x4 yacc[2][8] = {};
    f16* Wlw = Wl + w * (32 * 36);
    stage(0, jbase);
    __syncthreads();
    for (int jt = 0; jt < 16; jt++) {
        int bf = jt & 1;
        if (jt + 1 < 16) stage(bf ^ 1, jbase + (jt + 1) * 64);
#pragma unroll
        for (int jh = 0; jh < 2; jh++) {
#pragma unroll
            for (int js2 = 0; js2 < 2; js2++) {
                int js = jh * 2 + js2;
                f32x4 f0 = {0,0,0,0}, f1 = {0,0,0,0};
#pragma unroll
                for (int kk = 0; kk < 4; kk++) {
                    f16x8 pv = *reinterpret_cast<const f16x8*>(
                        &phiS[bf][(js * 16 + l16) * 128 + (((kk * 4 + q) ^ l16) * 8)]);
                    f0 = MFMA(ta[0][kk], pv, f0);
                    f1 = MFMA(ta[1][kk], pv, f1);
                }
                float mdv = __logf(Dpb[jbase + jt * 64 + js * 16 + l16]);
#pragma unroll
                for (int r = 0; r < 4; r++) {
                    Wlw[(q * 4 + r) * 36 + js2 * 16 + l16]      = (f16)__expf(f0[r] - mdv);
                    Wlw[(16 + q * 4 + r) * 36 + js2 * 16 + l16] = (f16)__expf(f1[r] - mdv);
                }
            }
            f16x8 wf0 = *reinterpret_cast<const f16x8*>(&Wlw[l16 * 36 + q * 8]);
            f16x8 wf1 = *reinterpret_cast<const f16x8*>(&Wlw[(16 + l16) * 36 + q * 8]);
#pragma unroll
            for (int d = 0; d < 8; d++) {
                f16x8 gv = *reinterpret_cast<const f16x8*>(
                    &gS[bf][(d * 16 + l16) * 64 + (((jh * 4 + q) ^ (l16 & 7)) * 8)]);
                yacc[0][d] = MFMA(wf0, gv, yacc[0][d]);
                yacc[1][d] = MFMA(wf1, gv, yacc[1][d]);
            }
        }
        __syncthreads();
    }
    f16* yw = yTr + w * (32 * 136);
#pragma unroll
    for (int s = 0; s < 2; s++)
#pragma unroll
        for (int d = 0; d < 8; d++)
#pragma unroll
            for (int r = 0; r < 4; r++)
                yw[(s * 16 + q * 4 + r) * 136 + d * 16 + l16] = (f16)yacc[s][d][r];
    f16* yo = yP + (size_t)jq * PSZ + ((size_t)bb * N_ + i0 + w * 32) * CI;
#pragma unroll
    for (int rr = 0; rr < 8; rr++) {
        int chunk = rr * 64 + l;
        int il = chunk >> 4, u = chunk & 15;
        *reinterpret_cast<f16x8*>(yo + il * CI + u * 8) =
            *reinterpret_cast<const f16x8*>(&yw[il * 136 + u * 8]);
    }
}

// ---------------- pass 4: w_y = wz @ (sum of y partials) + b, channel sums ----------------
// grid 2048: nb(128 n-tiles of 32) x ob(4) x bb(4); 8 blocks/CU.
__global__ __launch_bounds__(256) void k_wz(
        const f16* __restrict__ wzc, const f16* __restrict__ yP,
        const float* __restrict__ zb, f16* __restrict__ wy,
        float* __restrict__ ssum, float* __restrict__ ssq) {
    int id = blockIdx.x;                  // 2048
    int nb = id & 127, ob = (id >> 7) & 3, bb = id >> 9;
    int t = threadIdx.x, w = t >> 6, l16 = t & 15, q = (t & 63) >> 4;
    int o0 = ob * 64 + w * 16, n0 = nb * 32;
    f32x4 acc[2] = {};
#pragma unroll
    for (int kk = 0; kk < 4; kk++) {
        f16x8 av = *reinterpret_cast<const f16x8*>(wzc + (o0 + l16) * CI + kk * 32 + q * 8);
#pragma unroll
        for (int nt = 0; nt < 2; nt++) {
            size_t yi = ((size_t)bb * N_ + n0 + nt * 16 + l16) * CI + kk * 32 + q * 8;
            f16x8 b0 = *reinterpret_cast<const f16x8*>(yP + yi);
            f16x8 b1 = *reinterpret_cast<const f16x8*>(yP + PSZ + yi);
            f16x8 b2 = *reinterpret_cast<const f16x8*>(yP + 2 * PSZ + yi);
            f16x8 b3 = *reinterpret_cast<const f16x8*>(yP + 3 * PSZ + yi);
            f16x8 bv = (b0 + b1) + (b2 + b3);
            acc[nt] = MFMA(av, bv, acc[nt]);
        }
    }
#pragma unroll
    for (int r = 0; r < 4; r++) {
        int o = o0 + q * 4 + r;
        float bias = zb[o];
        float sr = 0.f, qr = 0.f;
#pragma unroll
        for (int nt = 0; nt < 2; nt++) {
            float v = acc[nt][r] + bias;
            wy[((size_t)bb * C_ + o) * N_ + n0 + nt * 16 + l16] = (f16)v;
            sr += v; qr += v * v;
        }
#pragma unroll
        for (int off = 1; off < 16; off <<= 1) {
            sr += __shfl_xor(sr, off);
            qr += __shfl_xor(qr, off);
        }
        if (l16 == 0) { atomicAdd(&ssum[o], sr); atomicAdd(&ssq[o], qr); }
    }
}

// ---------------- pass 5: BN (stats inline) + residual ----------------
__global__ void k_final(const f16* __restrict__ wy, const float* __restrict__ x,
                        const float* __restrict__ ssum, const float* __restrict__ ssq,
                        const float* __restrict__ gamma, const float* __restrict__ beta,
                        float* __restrict__ out) {
    int p = blockIdx.x * 256 + threadIdx.x;           // 512K groups of 8
    int c = (p >> 9) & 255;
    const float inv = 1.0f / 16384.0f;
    float mean = ssum[c] * inv;
    float var = ssq[c] * inv - mean * mean;
    float s = gamma[c] * rsqrtf(var + 1e-5f);
    float h = beta[c] - mean * s;
    f16x8 wv = reinterpret_cast<const f16x8*>(wy)[p];
    float4 x0 = reinterpret_cast<const float4*>(x)[2 * p];
    float4 x1 = reinterpret_cast<const float4*>(x)[2 * p + 1];
    float4 o0, o1;
    o0.x = (float)wv[0] * s + h + x0.x;
    o0.y = (float)wv[1] * s + h + x0.y;
    o0.z = (float)wv[2] * s + h + x0.z;
    o0.w = (float)wv[3] * s + h + x0.w;
    o1.x = (float)wv[4] * s + h + x1.x;
    o1.y = (float)wv[5] * s + h + x1.y;
    o1.z = (float)wv[6] * s + h + x1.z;
    o1.w = (float)wv[7] * s + h + x1.w;
    reinterpret_cast<float4*>(out)[2 * p] = o0;
    reinterpret_cast<float4*>(out)[2 * p + 1] = o1;
}

extern "C" void kernel_launch(void* const* d_in, const int* in_sizes, int n_in,
                              void* d_out, int out_size, void* d_ws, size_t ws_size,
                              hipStream_t stream) {
    const float* x     = (const float*)d_in[0];
    const float* gw    = (const float*)d_in[1];
    const float* gb    = (const float*)d_in[2];
    const float* tw    = (const float*)d_in[3];
    const float* tbv   = (const float*)d_in[4];
    const float* pw    = (const float*)d_in[5];
    const float* pb    = (const float*)d_in[6];
    const float* zw    = (const float*)d_in[7];
    const float* zb    = (const float*)d_in[8];
    const float* gamma = (const float*)d_in[9];
    const float* beta  = (const float*)d_in[10];

    char* ws = (char*)d_ws;
    f16* thetaT = (f16*)(ws + OFF_THETA);
    f16* phiT   = (f16*)(ws + OFF_PHI);
    f16* gC     = (f16*)(ws + OFF_G);
    f16* yP     = (f16*)(ws + OFF_YP);
    f16* wy     = (f16*)(ws + OFF_WY);
    f16* wcvt   = (f16*)(ws + OFF_WCVT);
    float* D    = (float*)(ws + OFF_D);
    float* ssum = (float*)(ws + OFF_SSUM);
    float* ssq  = (float*)(ws + OFF_SSQ);

    k_init<<<578, 256, 0, stream>>>(gw, tw, pw, zw, wcvt, D, ssum, ssq);
    k_proj<<<dim3(512, 3), 256, 0, stream>>>(x, wcvt, gb, tbv, pb, thetaT, phiT, gC);
    k_cols<<<1024, 256, 0, stream>>>(thetaT, phiT, D);
    k_attn<<<512, 256, 0, stream>>>(thetaT, phiT, gC, D, yP);
    k_wz<<<2048, 256, 0, stream>>>(wcvt + 3 * 32768, yP, zb, wy, ssum, ssq);
    k_final<<<2048, 256, 0, stream>>>(wy, x, ssum, ssq, gamma, beta, (float*)d_out);
}

// Round 9
// 213.078 us; speedup vs baseline: 1.5289x; 1.1834x over previous
//
#include <hip/hip_runtime.h>

// NonLocalBlock: B=4, C=256, Ci=128, H=W=64, N=4096.
// R9: all global atomics eliminated (R8 showed k_wz 68us with 0.6% MfmaUtil =
// device-scope atomic serialization; k_cols had 4x the atomic count).
// k_cols -> plain ps[isp] writes + k_colmerge (md = log D); k_wz -> grid 256
// (yP read once) + psum partials + k_red; k_proj reverted to 3-proj loop.
// k_attn = R6 body (proven 67us), consumes md directly.

#define B_  4
#define C_  256
#define CI  128
#define N_  4096
#define NB  (B_*N_)     // 16384
#define ISPLIT 16
#define MB_ (1u<<20)

typedef _Float16 f16;
typedef f16   f16x8 __attribute__((ext_vector_type(8)));
typedef f16   f16x4 __attribute__((ext_vector_type(4)));
typedef float f32x4 __attribute__((ext_vector_type(4)));

#define MFMA(a,b,c) __builtin_amdgcn_mfma_f32_16x16x32_f16(a,b,c,0,0,0)

// async global->LDS, 16B per lane; LDS dest = wave-uniform base + lane*16
#define GLD16(g, lp) __builtin_amdgcn_global_load_lds( \
    (const __attribute__((address_space(1))) void*)(g), \
    (__attribute__((address_space(3))) void*)(lp), 16, 0, 0)

// ---- workspace byte offsets (~30 MB) ----
#define OFF_THETA  0                 // f16 [B][N][CI]  4 MB
#define OFF_PHI    (4u*MB_)          // f16 [B][N][CI]  4 MB
#define OFF_G      (8u*MB_)          // f16 [B][CI][N]  4 MB
#define OFF_YP     (12u*MB_)         // f16 [4][B][N][CI]  16 MB (j-quarter partials)
#define OFF_WY     0                 // f16 [B][C][N] 8 MB — overlays theta+phi (dead by k_wz)
#define OFF_MD     (28u*MB_)                  // f32 [NB] log D  (64 KB)
#define OFF_PS     (OFF_MD + 65536)           // f32 [ISPLIT][NB]  1 MB
#define OFF_PSUM   (OFF_PS + ISPLIT*NB*4)     // f32 [256][2][256]  512 KB
#define OFF_SSUM   (OFF_PSUM + 524288)
#define OFF_SSQ    (OFF_SSUM + 1024)
#define OFF_WCVT   (OFF_SSQ + 1024)           // f16 weights g,t,p,z  256 KB
#define PSZ ((size_t)B_*N_*CI)

// ---------------- init: weight cvt f32->f16 ----------------
__global__ void k_init(const float* gw, const float* tw, const float* pw,
                       const float* zw, f16* wcvt) {
    int i = blockIdx.x * 256 + threadIdx.x;          // 0..131071
    const float* s;
    int which = i >> 15;
    if (which == 0) s = gw; else if (which == 1) s = tw;
    else if (which == 2) s = pw; else s = zw;
    wcvt[i] = (f16)s[i & 32767];
}

// ---------------- fused 1x1-conv projections (all 3, one x read) ----------------
__global__ __launch_bounds__(256) void k_proj(
        const float* __restrict__ x, const f16* __restrict__ wcvt,
        const float* __restrict__ gb, const float* __restrict__ tb,
        const float* __restrict__ pb,
        f16* __restrict__ thetaT, f16* __restrict__ phiT, f16* __restrict__ gC) {
    __shared__ __align__(16) f16 xT[32 * 264];       // [n][c], stride 264
    int bb = blockIdx.x >> 7;
    int n0 = (blockIdx.x & 127) * 32;
    int t = threadIdx.x;

    const float* xb = x + (size_t)bb * C_ * N_;
    for (int rep = 0; rep < 8; rep++) {
        int lin = rep * 256 + t;
        int c = lin >> 3, np = (lin & 7) * 4;
        float4 v = *reinterpret_cast<const float4*>(xb + c * N_ + n0 + np);
        xT[(np + 0) * 264 + c] = (f16)v.x;
        xT[(np + 1) * 264 + c] = (f16)v.y;
        xT[(np + 2) * 264 + c] = (f16)v.z;
        xT[(np + 3) * 264 + c] = (f16)v.w;
    }
    __syncthreads();

    int w = t >> 6, l16 = t & 15, q = (t & 63) >> 4;
    int ci0 = w * 32;
    for (int proj = 0; proj < 3; proj++) {
        const f16* W0 = wcvt + proj * 32768;         // [128][256] f16 row-major
        f32x4 acc[2][2] = {};
        for (int kk = 0; kk < 8; kk++) {
            f16x8 a0 = *reinterpret_cast<const f16x8*>(W0 + (ci0 + l16) * 256 + kk * 32 + q * 8);
            f16x8 a1 = *reinterpret_cast<const f16x8*>(W0 + (ci0 + 16 + l16) * 256 + kk * 32 + q * 8);
#pragma unroll
            for (int nt = 0; nt < 2; nt++) {
                f16x8 bv = *reinterpret_cast<const f16x8*>(&xT[(nt * 16 + l16) * 264 + kk * 32 + q * 8]);
                acc[0][nt] = MFMA(a0, bv, acc[0][nt]);
                acc[1][nt] = MFMA(a1, bv, acc[1][nt]);
            }
        }
        const float* bias = (proj == 0) ? gb : (proj == 1) ? tb : pb;
#pragma unroll
        for (int a = 0; a < 2; a++) {
#pragma unroll
            for (int nt = 0; nt < 2; nt++) {
                int n = n0 + nt * 16 + l16;
                int cib = ci0 + a * 16 + q * 4;
                if (proj == 0) {
#pragma unroll
                    for (int r = 0; r < 4; r++)
                        gC[((size_t)bb * CI + cib + r) * N_ + n] = (f16)(acc[a][nt][r] + bias[cib + r]);
                } else {
                    f16x4 v4;
#pragma unroll
                    for (int r = 0; r < 4; r++) v4[r] = (f16)(acc[a][nt][r] + bias[cib + r]);
                    f16* dst = (proj == 1 ? thetaT : phiT) + ((size_t)bb * N_ + n) * CI + cib;
                    *reinterpret_cast<f16x4*>(dst) = v4;
                }
            }
        }
    }
}

// ---------------- pass 2: column exp-sums, plain ps writes ----------------
// grid 1024 = bb(4) x jb(16) x isp(16); i-slice 256 = 4 staged tiles of 64.
__global__ __launch_bounds__(256, 2) void k_cols(
        const f16* __restrict__ thetaT, const f16* __restrict__ phiT,
        float* __restrict__ ps) {
    __shared__ __align__(16) f16 thS[2][64 * 128];
    int id = blockIdx.x;                 // 1024
    int isp = id & 15, jb = (id >> 4) & 15, bb = id >> 8;
    int t = threadIdx.x, w = t >> 6, l = t & 63, l16 = t & 15, q = (t & 63) >> 4;
    int jw0 = jb * 256 + w * 64;

    f16x8 pf[4][4];
    const f16* pb = phiT + ((size_t)bb * N_ + jw0) * CI;
#pragma unroll
    for (int jt = 0; jt < 4; jt++)
#pragma unroll
        for (int kk = 0; kk < 4; kk++)
            pf[jt][kk] = *reinterpret_cast<const f16x8*>(pb + (jt * 16 + l16) * CI + kk * 32 + q * 8);

    const f16* thB = thetaT + ((size_t)bb * N_ + isp * 256) * CI;
    auto stage = [&](int bf, int it0) {
#pragma unroll
        for (int r = 0; r < 4; r++) {
            int p = r * 256 + w * 64 + l;
            int pi = p >> 4, pu = (p & 15) ^ (pi & 15);
            const char* ga = (const char*)(thB + (size_t)(it0 + pi) * CI) + pu * 16;
            GLD16(ga, &thS[bf][(r * 256 + w * 64) * 8]);
        }
    };

    float s[4] = {0.f, 0.f, 0.f, 0.f};
    stage(0, 0);
    __syncthreads();
    for (int it = 0; it < 4; it++) {
        int bf = it & 1;
        if (it + 1 < 4) stage(bf ^ 1, (it + 1) * 64);
#pragma unroll
        for (int ic = 0; ic < 4; ic++) {
            f16x8 av[4];
#pragma unroll
            for (int kk = 0; kk < 4; kk++)
                av[kk] = *reinterpret_cast<const f16x8*>(
                    &thS[bf][(ic * 16 + l16) * 128 + (((kk * 4 + q) ^ l16) * 8)]);
            f32x4 f[4] = {};
#pragma unroll
            for (int kk = 0; kk < 4; kk++)
#pragma unroll
                for (int jt = 0; jt < 4; jt++)
                    f[jt] = MFMA(av[kk], pf[jt][kk], f[jt]);
#pragma unroll
            for (int jt = 0; jt < 4; jt++)
                s[jt] += __expf(f[jt][0]) + __expf(f[jt][1])
                       + __expf(f[jt][2]) + __expf(f[jt][3]);
        }
        __syncthreads();
    }
#pragma unroll
    for (int jt = 0; jt < 4; jt++) {
        s[jt] += __shfl_xor(s[jt], 16);
        s[jt] += __shfl_xor(s[jt], 32);
    }
    if (q == 0) {
#pragma unroll
        for (int jt = 0; jt < 4; jt++)
            ps[isp * NB + bb * N_ + jw0 + jt * 16 + l16] = s[jt];
    }
}

// ---------------- merge: md[j] = log(sum_isp ps) ----------------
__global__ void k_colmerge(const float* __restrict__ ps, float* __restrict__ md) {
    int j = blockIdx.x * 256 + threadIdx.x;          // 0..16383
    float s = 0.f;
    for (int isp = 0; isp < ISPLIT; isp++) s += ps[isp * NB + j];
    md[j] = __logf(s);
}

// ---------------- pass 3: y = softmax(f) @ g  (R6 body, md precomputed) ----------------
__global__ __launch_bounds__(256, 2) void k_attn(
        const f16* __restrict__ thetaT, const f16* __restrict__ phiT,
        const f16* __restrict__ gC, const float* __restrict__ md,
        f16* __restrict__ yP) {
    __shared__ __align__(16) char smem[74752];
    f16 (*phiS)[64 * 128] = (f16(*)[64 * 128])smem;            // 2 x 16 KB
    f16 (*gS)[128 * 64]   = (f16(*)[128 * 64])(smem + 32768);  // 2 x 16 KB
    f16* Wl  = (f16*)(smem + 65536);                           // 4 x [32][36] = 9 KB
    f16* yTr = (f16*)smem;                                     // epilogue overlay

    int jq = blockIdx.x & 3;
    int ib = blockIdx.x >> 2;          // 0..127
    int bb = ib >> 5;
    int i0 = (ib & 31) * 128;
    int t = threadIdx.x, w = t >> 6, l = t & 63, l16 = t & 15, q = (t & 63) >> 4;
    int jbase = jq * 1024;

    f16x8 ta[2][4];
    const f16* tb = thetaT + ((size_t)bb * N_ + i0 + w * 32 + l16) * CI;
#pragma unroll
    for (int s = 0; s < 2; s++)
#pragma unroll
        for (int kk = 0; kk < 4; kk++)
            ta[s][kk] = *reinterpret_cast<const f16x8*>(tb + s * 16 * CI + kk * 32 + q * 8);

    const f16* phiB = phiT + (size_t)bb * N_ * CI;
    const f16* gB   = gC   + (size_t)bb * CI * N_;
    const float* mdb = md + bb * N_;

    auto stage = [&](int bf, int j0g) {
#pragma unroll
        for (int r = 0; r < 4; r++) {
            int p = r * 256 + w * 64 + l;
            int ub = (r * 256 + w * 64) * 8;          // wave-uniform LDS base (f16)
            int pj = p >> 4, pu = (p & 15) ^ (pj & 15);
            const char* ga = (const char*)(phiB + (size_t)(j0g + pj) * CI) + pu * 16;
            GLD16(ga, &phiS[bf][ub]);
            int pc = p >> 3, pu2 = (p & 7) ^ (pc & 7);
            const char* ga2 = (const char*)(gB + (size_t)pc * N_ + j0g) + pu2 * 16;
            GLD16(ga2, &gS[bf][ub]);
        }
    };

    f32x4 yacc[2][8] = {};
    f16* Wlw = Wl + w * (32 * 36);
    stage(0, jbase);
    __syncthreads();
    for (int jt = 0; jt < 16; jt++) {
        int bf = jt & 1;
        if (jt + 1 < 16) stage(bf ^ 1, jbase + (jt + 1) * 64);
#pragma unroll
        for (int jh = 0; jh < 2; jh++) {
#pragma unroll
            for (int js2 = 0; js2 < 2; js2++) {
                int js = jh * 2 + js2;
                f32x4 f0 = {0,0,0,0}, f1 = {0,0,0,0};
#pragma unroll
                for (int kk = 0; kk < 4; kk++) {
                    f16x8 pv = *reinterpret_cast<const f16x8*>(
                        &phiS[bf][(js * 16 + l16) * 128 + (((kk * 4 + q) ^ l16) * 8)]);
                    f0 = MFMA(ta[0][kk], pv, f0);
                    f1 = MFMA(ta[1][kk], pv, f1);
                }
                float mdv = mdb[jbase + jt * 64 + js * 16 + l16];
#pragma unroll
                for (int r = 0; r < 4; r++) {
                    Wlw[(q * 4 + r) * 36 + js2 * 16 + l16]      = (f16)__expf(f0[r] - mdv);
                    Wlw[(16 + q * 4 + r) * 36 + js2 * 16 + l16] = (f16)__expf(f1[r] - mdv);
                }
            }
            f16x8 wf0 = *reinterpret_cast<const f16x8*>(&Wlw[l16 * 36 + q * 8]);
            f16x8 wf1 = *reinterpret_cast<const f16x8*>(&Wlw[(16 + l16) * 36 + q * 8]);
#pragma unroll
            for (int d = 0; d < 8; d++) {
                f16x8 gv = *reinterpret_cast<const f16x8*>(
                    &gS[bf][(d * 16 + l16) * 64 + (((jh * 4 + q) ^ (l16 & 7)) * 8)]);
                yacc[0][d] = MFMA(wf0, gv, yacc[0][d]);
                yacc[1][d] = MFMA(wf1, gv, yacc[1][d]);
            }
        }
        __syncthreads();
    }
    f16* yw = yTr + w * (32 * 136);
#pragma unroll
    for (int s = 0; s < 2; s++)
#pragma unroll
        for (int d = 0; d < 8; d++)
#pragma unroll
            for (int r = 0; r < 4; r++)
                yw[(s * 16 + q * 4 + r) * 136 + d * 16 + l16] = (f16)yacc[s][d][r];
    f16* yo = yP + (size_t)jq * PSZ + ((size_t)bb * N_ + i0 + w * 32) * CI;
#pragma unroll
    for (int rr = 0; rr < 8; rr++) {
        int chunk = rr * 64 + l;
        int il = chunk >> 4, u = chunk & 15;
        *reinterpret_cast<f16x8*>(yo + il * CI + u * 8) =
            *reinterpret_cast<const f16x8*>(&yw[il * 136 + u * 8]);
    }
}

// ---------------- pass 4: w_y = wz @ (sum of y partials) + b ----------------
// grid 256: block = bb(4) x nb(64 n-tiles of 64); reads its yP slice ONCE,
// computes all 256 output channels; per-block channel partials -> psum.
__global__ __launch_bounds__(256) void k_wz(
        const f16* __restrict__ wzc, const f16* __restrict__ yP,
        const float* __restrict__ zb, f16* __restrict__ wy,
        float* __restrict__ psum) {
    int id = blockIdx.x;                  // 256
    int nb = id & 63, bb = id >> 6;
    int t = threadIdx.x, w = t >> 6, l16 = t & 15, q = (t & 63) >> 4;
    int o0 = w * 64, n0 = nb * 64;
    f32x4 acc[4][4] = {};                 // [os][nt]
#pragma unroll
    for (int kk = 0; kk < 4; kk++) {
        f16x8 bv[4];
#pragma unroll
        for (int nt = 0; nt < 4; nt++) {
            size_t yi = ((size_t)bb * N_ + n0 + nt * 16 + l16) * CI + kk * 32 + q * 8;
            f16x8 b0 = *reinterpret_cast<const f16x8*>(yP + yi);
            f16x8 b1 = *reinterpret_cast<const f16x8*>(yP + PSZ + yi);
            f16x8 b2 = *reinterpret_cast<const f16x8*>(yP + 2 * PSZ + yi);
            f16x8 b3 = *reinterpret_cast<const f16x8*>(yP + 3 * PSZ + yi);
            bv[nt] = (b0 + b1) + (b2 + b3);
        }
#pragma unroll
        for (int os = 0; os < 4; os++) {
            f16x8 av = *reinterpret_cast<const f16x8*>(
                wzc + (o0 + os * 16 + l16) * CI + kk * 32 + q * 8);
#pragma unroll
            for (int nt = 0; nt < 4; nt++)
                acc[os][nt] = MFMA(av, bv[nt], acc[os][nt]);
        }
    }
#pragma unroll
    for (int os = 0; os < 4; os++)
#pragma unroll
    for (int r = 0; r < 4; r++) {
        int o = o0 + os * 16 + q * 4 + r;
        float bias = zb[o];
        float sr = 0.f, qr = 0.f;
#pragma unroll
        for (int nt = 0; nt < 4; nt++) {
            float v = acc[os][nt][r] + bias;
            wy[((size_t)bb * C_ + o) * N_ + n0 + nt * 16 + l16] = (f16)v;
            sr += v; qr += v * v;
        }
#pragma unroll
        for (int off = 1; off < 16; off <<= 1) {
            sr += __shfl_xor(sr, off);
            qr += __shfl_xor(qr, off);
        }
        if (l16 == 0) {
            psum[(o * 2 + 0) * 256 + id] = sr;
            psum[(o * 2 + 1) * 256 + id] = qr;
        }
    }
}

// ---------------- reduce psum -> ssum/ssq ----------------
__global__ void k_red(const float* __restrict__ psum, float* __restrict__ ssum,
                      float* __restrict__ ssq) {
    int b = blockIdx.x;                   // 0: ssum, 1: ssq
    int o = threadIdx.x;
    const float* src = psum + (o * 2 + b) * 256;
    float s = 0.f;
    for (int k = 0; k < 64; k++) {
        float4 v = reinterpret_cast<const float4*>(src)[k];
        s += v.x + v.y + v.z + v.w;
    }
    (b == 0 ? ssum : ssq)[o] = s;
}

// ---------------- pass 5: BN (stats inline) + residual ----------------
__global__ void k_final(const f16* __restrict__ wy, const float* __restrict__ x,
                        const float* __restrict__ ssum, const float* __restrict__ ssq,
                        const float* __restrict__ gamma, const float* __restrict__ beta,
                        float* __restrict__ out) {
    int p = blockIdx.x * 256 + threadIdx.x;           // 512K groups of 8
    int c = (p >> 9) & 255;
    const float inv = 1.0f / 16384.0f;
    float mean = ssum[c] * inv;
    float var = ssq[c] * inv - mean * mean;
    float s = gamma[c] * rsqrtf(var + 1e-5f);
    float h = beta[c] - mean * s;
    f16x8 wv = reinterpret_cast<const f16x8*>(wy)[p];
    float4 x0 = reinterpret_cast<const float4*>(x)[2 * p];
    float4 x1 = reinterpret_cast<const float4*>(x)[2 * p + 1];
    float4 o0, o1;
    o0.x = (float)wv[0] * s + h + x0.x;
    o0.y = (float)wv[1] * s + h + x0.y;
    o0.z = (float)wv[2] * s + h + x0.z;
    o0.w = (float)wv[3] * s + h + x0.w;
    o1.x = (float)wv[4] * s + h + x1.x;
    o1.y = (float)wv[5] * s + h + x1.y;
    o1.z = (float)wv[6] * s + h + x1.z;
    o1.w = (float)wv[7] * s + h + x1.w;
    reinterpret_cast<float4*>(out)[2 * p] = o0;
    reinterpret_cast<float4*>(out)[2 * p + 1] = o1;
}

extern "C" void kernel_launch(void* const* d_in, const int* in_sizes, int n_in,
                              void* d_out, int out_size, void* d_ws, size_t ws_size,
                              hipStream_t stream) {
    const float* x     = (const float*)d_in[0];
    const float* gw    = (const float*)d_in[1];
    const float* gb    = (const float*)d_in[2];
    const float* tw    = (const float*)d_in[3];
    const float* tbv   = (const float*)d_in[4];
    const float* pw    = (const float*)d_in[5];
    const float* pb    = (const float*)d_in[6];
    const float* zw    = (const float*)d_in[7];
    const float* zb    = (const float*)d_in[8];
    const float* gamma = (const float*)d_in[9];
    const float* beta  = (const float*)d_in[10];

    char* ws = (char*)d_ws;
    f16* thetaT = (f16*)(ws + OFF_THETA);
    f16* phiT   = (f16*)(ws + OFF_PHI);
    f16* gC     = (f16*)(ws + OFF_G);
    f16* yP     = (f16*)(ws + OFF_YP);
    f16* wy     = (f16*)(ws + OFF_WY);
    f16* wcvt   = (f16*)(ws + OFF_WCVT);
    float* md   = (float*)(ws + OFF_MD);
    float* ps   = (float*)(ws + OFF_PS);
    float* psum = (float*)(ws + OFF_PSUM);
    float* ssum = (float*)(ws + OFF_SSUM);
    float* ssq  = (float*)(ws + OFF_SSQ);

    k_init<<<512, 256, 0, stream>>>(gw, tw, pw, zw, wcvt);
    k_proj<<<512, 256, 0, stream>>>(x, wcvt, gb, tbv, pb, thetaT, phiT, gC);
    k_cols<<<1024, 256, 0, stream>>>(thetaT, phiT, ps);
    k_colmerge<<<64, 256, 0, stream>>>(ps, md);
    k_attn<<<512, 256, 0, stream>>>(thetaT, phiT, gC, md, yP);
    k_wz<<<256, 256, 0, stream>>>(wcvt + 3 * 32768, yP, zb, wy, psum);
    k_red<<<2, 256, 0, stream>>>(psum, ssum, ssq);
    k_final<<<2048, 256, 0, stream>>>(wy, x, ssum, ssq, gamma, beta, (float*)d_out);
}